// Round 1
// baseline (1672.066 us; speedup 1.0000x reference)
//
#include <hip/hip_runtime.h>
#include <hip/hip_bf16.h>
#include <stdint.h>

typedef __bf16 bf16_t;
typedef __bf16 bf16x8 __attribute__((ext_vector_type(8)));
typedef float f32x4 __attribute__((ext_vector_type(4)));
typedef unsigned short u16;
typedef u16 u16x8 __attribute__((ext_vector_type(8)));

__device__ __forceinline__ u16 f2bf(float f) {
    uint32_t u = __builtin_bit_cast(uint32_t, f);
    u += 0x7FFFu + ((u >> 16) & 1u);   // round-to-nearest-even
    return (u16)(u >> 16);
}
__device__ __forceinline__ float bf2f(u16 h) {
    return __builtin_bit_cast(float, (uint32_t)h << 16);
}

// ---------------------------------------------------------------- converts
__global__ void k_f32_to_bf16(const float* __restrict__ in, u16* __restrict__ out, int n4) {
    int i = blockIdx.x * blockDim.x + threadIdx.x;
    int stride = gridDim.x * blockDim.x;
    for (; i < n4; i += stride) {
        float4 v = ((const float4*)in)[i];
        ushort4 o;
        o.x = f2bf(v.x); o.y = f2bf(v.y); o.z = f2bf(v.z); o.w = f2bf(v.w);
        ((ushort4*)out)[i] = o;
    }
}

// ---------------------------------------------------------------- GEMM (C = A * B^T), A:MxK bf16, B:NxK bf16, C:MxN
// m97-lineage: 128x128 tile, BK=32, 4 waves (2x2), 16 MFMA 16x16x32 per K-step,
// global_load_lds width=16 staging, linear LDS.
template <typename OutT>
__global__ __launch_bounds__(256) void k_gemm_bt(
    const u16* __restrict__ A, const u16* __restrict__ Bm,
    OutT* __restrict__ C, int M, int N, int K)
{
    __shared__ u16 lA[128 * 32];
    __shared__ u16 lB[128 * 32];

    const int t = threadIdx.x;
    const int lane = t & 63;
    const int wave = t >> 6;
    const int wr = wave >> 1, wc = wave & 1;     // 2x2 waves -> 64x64 each
    const int bm = blockIdx.y * 128, bn = blockIdx.x * 128;

    // staging: thread t loads 16B chunk t -> LDS row t/4, col8 (t%4)*8
    const int srow = t >> 2;
    const int scol = (t & 3) * 8;
    const size_t a0 = (size_t)(bm + srow) * K + scol;
    const size_t a1 = (size_t)(bm + 64 + srow) * K + scol;
    const size_t b0 = (size_t)(bn + srow) * K + scol;
    const size_t b1 = (size_t)(bn + 64 + srow) * K + scol;

    // fragment read pattern: row = lane&15, k = (lane>>4)*8
    const int fr = lane & 15;
    const int fk = (lane >> 4) * 8;

    f32x4 acc[4][4];
    const f32x4 fzero = {0.f, 0.f, 0.f, 0.f};
#pragma unroll
    for (int i = 0; i < 4; ++i)
#pragma unroll
        for (int j = 0; j < 4; ++j) acc[i][j] = fzero;

    u16* ldsA = lA + wave * 512;   // wave-uniform base; HW adds lane*16B
    u16* ldsB = lB + wave * 512;

    for (int k0 = 0; k0 < K; k0 += 32) {
        __builtin_amdgcn_global_load_lds(
            (const __attribute__((address_space(1))) void*)(A + a0 + k0),
            (__attribute__((address_space(3))) void*)(ldsA), 16, 0, 0);
        __builtin_amdgcn_global_load_lds(
            (const __attribute__((address_space(1))) void*)(A + a1 + k0),
            (__attribute__((address_space(3))) void*)(ldsA + 2048), 16, 0, 0);
        __builtin_amdgcn_global_load_lds(
            (const __attribute__((address_space(1))) void*)(Bm + b0 + k0),
            (__attribute__((address_space(3))) void*)(ldsB), 16, 0, 0);
        __builtin_amdgcn_global_load_lds(
            (const __attribute__((address_space(1))) void*)(Bm + b1 + k0),
            (__attribute__((address_space(3))) void*)(ldsB + 2048), 16, 0, 0);
        __syncthreads();

        bf16x8 af[4], bfv[4];
#pragma unroll
        for (int mi = 0; mi < 4; ++mi)
            af[mi] = *(const bf16x8*)&lA[(wr * 64 + mi * 16 + fr) * 32 + fk];
#pragma unroll
        for (int ni = 0; ni < 4; ++ni)
            bfv[ni] = *(const bf16x8*)&lB[(wc * 64 + ni * 16 + fr) * 32 + fk];
#pragma unroll
        for (int mi = 0; mi < 4; ++mi)
#pragma unroll
            for (int ni = 0; ni < 4; ++ni)
                acc[mi][ni] = __builtin_amdgcn_mfma_f32_16x16x32_bf16(
                    af[mi], bfv[ni], acc[mi][ni], 0, 0, 0);
        __syncthreads();
    }

    // epilogue: C/D layout col=lane&15, row=(lane>>4)*4+r  [m89/m91]
    const int cr = (lane >> 4) * 4;
    const int cc = lane & 15;
#pragma unroll
    for (int mi = 0; mi < 4; ++mi) {
#pragma unroll
        for (int ni = 0; ni < 4; ++ni) {
            const int row = bm + wr * 64 + mi * 16 + cr;
            const int col = bn + wc * 64 + ni * 16 + cc;
#pragma unroll
            for (int r = 0; r < 4; ++r) {
                float val = acc[mi][ni][r];
                size_t idx = (size_t)(row + r) * N + col;
                if constexpr (sizeof(OutT) == 2) ((u16*)C)[idx] = f2bf(val);
                else                             ((float*)C)[idx] = val;
            }
        }
    }
}

// ---------------------------------------------------------------- RoPE in place on (B*S, H*128) bf16
__global__ void k_rope(u16* __restrict__ x, int S, int n) {
    int i = blockIdx.x * blockDim.x + threadIdx.x;
    if (i >= n) return;
    const int j = i & 63;          // pair index within head dim
    const int h = (i >> 6) & 15;
    const int row = i >> 10;       // b*S + s
    const int s = row & (S - 1);
    // inv_freq = 10000^(-2j/128) = exp2(-(2j/128)*log2(10000))
    const float L2B = 13.287712379549449f;
    float inv = exp2f(-(float)(2 * j) * (L2B / 128.f));
    float ang = (float)s * inv;
    float c, sn;
    sincosf(ang, &sn, &c);
    size_t base = (size_t)row * 2048 + h * 128 + j;
    float x1 = bf2f(x[base]);
    float x2 = bf2f(x[base + 64]);
    x[base]      = f2bf(x1 * c - x2 * sn);
    x[base + 64] = f2bf(x2 * c + x1 * sn);
}

// ---------------------------------------------------------------- causal flash attention, fp32 compute
#define QB 64
#define KB 64
#define LD 132     // padded fp32 row stride (float4-aligned, conflict-friendly)
#define LDP 66

__global__ __launch_bounds__(256) void k_flash(
    const u16* __restrict__ Q, const u16* __restrict__ K, const u16* __restrict__ V,
    u16* __restrict__ O, int Bb, int S, int H)
{
    __shared__ float Qt[QB * LD];
    __shared__ float Kt[KB * LD];
    __shared__ float Vt[KB * LD];
    __shared__ float Pt[QB * LDP];

    const int t = threadIdx.x;
    const int tx = t & 15, ty = t >> 4;
    const int nqt = S / QB;
    int blk = blockIdx.x;
    const int qt = blk % nqt; blk /= nqt;
    const int h = blk % H;
    const int b = blk / H;
    const int q0 = qt * QB;
    const int HD = H * 128;
    const u16* qb = Q + (size_t)b * S * HD + h * 128;
    const u16* kb = K + (size_t)b * S * HD + h * 128;
    const u16* vb = V + (size_t)b * S * HD + h * 128;

    // stage Q tile (bf16 -> fp32)
    for (int i = t; i < QB * 16; i += 256) {
        int row = i >> 4, c8 = (i & 15) * 8;
        u16x8 u = *(const u16x8*)(qb + (size_t)(q0 + row) * HD + c8);
#pragma unroll
        for (int j = 0; j < 8; ++j) Qt[row * LD + c8 + j] = bf2f(u[j]);
    }

    float m[4], l[4], acco[4][8];
#pragma unroll
    for (int r = 0; r < 4; ++r) {
        m[r] = -1e30f; l[r] = 0.f;
#pragma unroll
        for (int d = 0; d < 8; ++d) acco[r][d] = 0.f;
    }

    const float scale = 0.08838834764831845f;   // 1/sqrt(128)

    for (int j0 = 0; j0 <= q0; j0 += KB) {
        __syncthreads();   // Q staged / prev PV done
        for (int i = t; i < KB * 16; i += 256) {
            int row = i >> 4, c8 = (i & 15) * 8;
            u16x8 uk = *(const u16x8*)(kb + (size_t)(j0 + row) * HD + c8);
            u16x8 uv = *(const u16x8*)(vb + (size_t)(j0 + row) * HD + c8);
#pragma unroll
            for (int j = 0; j < 8; ++j) {
                Kt[row * LD + c8 + j] = bf2f(uk[j]);
                Vt[row * LD + c8 + j] = bf2f(uv[j]);
            }
        }
        __syncthreads();

        // scores: rows ty*4+r, cols tx+16*c
        float sc[4][4];
#pragma unroll
        for (int r = 0; r < 4; ++r)
#pragma unroll
            for (int c = 0; c < 4; ++c) sc[r][c] = 0.f;

        for (int d = 0; d < 128; d += 4) {
            float4 qv[4], kv[4];
#pragma unroll
            for (int r = 0; r < 4; ++r) qv[r] = *(const float4*)&Qt[(ty * 4 + r) * LD + d];
#pragma unroll
            for (int c = 0; c < 4; ++c) kv[c] = *(const float4*)&Kt[(tx + 16 * c) * LD + d];
#pragma unroll
            for (int r = 0; r < 4; ++r)
#pragma unroll
                for (int c = 0; c < 4; ++c)
                    sc[r][c] += qv[r].x * kv[c].x + qv[r].y * kv[c].y +
                                qv[r].z * kv[c].z + qv[r].w * kv[c].w;
        }

        // online softmax
#pragma unroll
        for (int r = 0; r < 4; ++r) {
            const int gi = q0 + ty * 4 + r;
            float rowmax = -1e30f;
#pragma unroll
            for (int c = 0; c < 4; ++c) {
                const int gj = j0 + tx + 16 * c;
                sc[r][c] = (gj > gi) ? -1e30f : sc[r][c] * scale;
                rowmax = fmaxf(rowmax, sc[r][c]);
            }
            for (int off = 8; off; off >>= 1) rowmax = fmaxf(rowmax, __shfl_xor(rowmax, off));
            const float mn = fmaxf(m[r], rowmax);
            const float alpha = __expf(m[r] - mn);
            m[r] = mn;
            float rs = 0.f;
#pragma unroll
            for (int c = 0; c < 4; ++c) {
                float pp = __expf(sc[r][c] - mn);
                sc[r][c] = pp;
                rs += pp;
            }
            for (int off = 8; off; off >>= 1) rs += __shfl_xor(rs, off);
            l[r] = l[r] * alpha + rs;
#pragma unroll
            for (int d = 0; d < 8; ++d) acco[r][d] *= alpha;
#pragma unroll
            for (int c = 0; c < 4; ++c) Pt[(ty * 4 + r) * LDP + tx + 16 * c] = sc[r][c];
        }
        __syncthreads();

        // PV: thread owns rows ty*4..+4, cols d = tx*4..+4 and 64+tx*4..+4
        for (int kk = 0; kk < KB; ++kk) {
            float4 v0 = *(const float4*)&Vt[kk * LD + tx * 4];
            float4 v1 = *(const float4*)&Vt[kk * LD + 64 + tx * 4];
#pragma unroll
            for (int r = 0; r < 4; ++r) {
                float p = Pt[(ty * 4 + r) * LDP + kk];
                acco[r][0] += p * v0.x; acco[r][1] += p * v0.y;
                acco[r][2] += p * v0.z; acco[r][3] += p * v0.w;
                acco[r][4] += p * v1.x; acco[r][5] += p * v1.y;
                acco[r][6] += p * v1.z; acco[r][7] += p * v1.w;
            }
        }
    }

    // epilogue
#pragma unroll
    for (int r = 0; r < 4; ++r) {
        float inv = 1.f / l[r];
        size_t orow = (size_t)(b * S + q0 + ty * 4 + r) * HD + h * 128;
#pragma unroll
        for (int j = 0; j < 4; ++j) {
            O[orow + tx * 4 + j]      = f2bf(acco[r][j] * inv);
            O[orow + 64 + tx * 4 + j] = f2bf(acco[r][4 + j] * inv);
        }
    }
}

// ---------------------------------------------------------------- launch
extern "C" void kernel_launch(void* const* d_in, const int* in_sizes, int n_in,
                              void* d_out, int out_size, void* d_ws, size_t ws_size,
                              hipStream_t stream) {
    const float* hs = (const float*)d_in[0];
    const float* Wq = (const float*)d_in[1];
    const float* Wc = (const float*)d_in[2];
    const float* Wk = (const float*)d_in[3];
    const float* Wv = (const float*)d_in[4];
    const float* Wo = (const float*)d_in[5];

    const int B = 2, S = 2048, D = 2048, DL = 512, H = 16;
    const int M = B * S;   // 4096

    char* p = (char*)d_ws;
    u16* hs_bf = (u16*)p; p += (size_t)M * D * 2;
    u16* Wq_bf = (u16*)p; p += (size_t)D * D * 2;
    u16* Wc_bf = (u16*)p; p += (size_t)DL * D * 2;
    u16* Wk_bf = (u16*)p; p += (size_t)D * DL * 2;
    u16* Wv_bf = (u16*)p; p += (size_t)D * DL * 2;
    u16* Wo_bf = (u16*)p; p += (size_t)D * D * 2;
    u16* qb    = (u16*)p; p += (size_t)M * D * 2;
    u16* kb    = (u16*)p; p += (size_t)M * D * 2;
    u16* vb    = (u16*)p; p += (size_t)M * D * 2;
    u16* ckv   = (u16*)p; p += (size_t)M * DL * 2;
    u16* attn  = (u16*)p; p += (size_t)M * D * 2;

    auto conv = [&](const float* in, u16* out, size_t n) {
        int n4 = (int)(n / 4);
        int blocks = (n4 + 255) / 256;
        if (blocks > 4096) blocks = 4096;
        k_f32_to_bf16<<<blocks, 256, 0, stream>>>(in, out, n4);
    };
    conv(hs, hs_bf, (size_t)M * D);
    conv(Wq, Wq_bf, (size_t)D * D);
    conv(Wc, Wc_bf, (size_t)DL * D);
    conv(Wk, Wk_bf, (size_t)D * DL);
    conv(Wv, Wv_bf, (size_t)D * DL);
    conv(Wo, Wo_bf, (size_t)D * D);

    // q = hs @ Wq^T  (M x D, K=D)
    k_gemm_bt<u16><<<dim3(D / 128, M / 128), 256, 0, stream>>>(hs_bf, Wq_bf, qb, M, D, D);
    // c_kv = hs @ Wc^T  (M x DL, K=D)
    k_gemm_bt<u16><<<dim3(DL / 128, M / 128), 256, 0, stream>>>(hs_bf, Wc_bf, ckv, M, DL, D);
    // k = c_kv @ Wk^T, v = c_kv @ Wv^T  (M x D, K=DL)
    k_gemm_bt<u16><<<dim3(D / 128, M / 128), 256, 0, stream>>>(ckv, Wk_bf, kb, M, D, DL);
    k_gemm_bt<u16><<<dim3(D / 128, M / 128), 256, 0, stream>>>(ckv, Wv_bf, vb, M, D, DL);

    {
        int n = M * H * 64;
        int blocks = (n + 255) / 256;
        k_rope<<<blocks, 256, 0, stream>>>(qb, S, n);
        k_rope<<<blocks, 256, 0, stream>>>(kb, S, n);
    }

    k_flash<<<B * H * (S / QB), 256, 0, stream>>>(qb, kb, vb, attn, B, S, H);

    // out = attn @ Wo^T  (fp32 out)
    k_gemm_bt<float><<<dim3(D / 128, M / 128), 256, 0, stream>>>(attn, Wo_bf, (float*)d_out, M, D, D);
}

// Round 2
// 367.999 us; speedup vs baseline: 4.5437x; 4.5437x over previous
//
#include <hip/hip_runtime.h>
#include <hip/hip_bf16.h>
#include <stdint.h>

typedef __bf16 bf16_t;
typedef __bf16 bf16x8 __attribute__((ext_vector_type(8)));
typedef float f32x4 __attribute__((ext_vector_type(4)));
typedef unsigned short u16;
typedef u16 u16x8 __attribute__((ext_vector_type(8)));
typedef u16 u16x4 __attribute__((ext_vector_type(4)));

__device__ __forceinline__ u16 f2bf(float f) {
    uint32_t u = __builtin_bit_cast(uint32_t, f);
    u += 0x7FFFu + ((u >> 16) & 1u);   // round-to-nearest-even
    return (u16)(u >> 16);
}
__device__ __forceinline__ float bf2f(u16 h) {
    return __builtin_bit_cast(float, (uint32_t)h << 16);
}

// ---------------------------------------------------------------- converts
__global__ void k_f32_to_bf16(const float* __restrict__ in, u16* __restrict__ out, int n4) {
    int i = blockIdx.x * blockDim.x + threadIdx.x;
    int stride = gridDim.x * blockDim.x;
    for (; i < n4; i += stride) {
        float4 v = ((const float4*)in)[i];
        ushort4 o;
        o.x = f2bf(v.x); o.y = f2bf(v.y); o.z = f2bf(v.z); o.w = f2bf(v.w);
        ((ushort4*)out)[i] = o;
    }
}

// ---------------------------------------------------------------- GEMM (C = A * B^T), A:MxK bf16, B:NxK bf16
// OUTMODE: 0 = bf16 MxN, 1 = f32 MxN, 2 = bf16 written as V^T (b,h,d,s) for attention
template <int OUTMODE>
__global__ __launch_bounds__(256) void k_gemm_bt(
    const u16* __restrict__ A, const u16* __restrict__ Bm,
    void* __restrict__ C, int M, int N, int K)
{
    __shared__ u16 lA[128 * 32];
    __shared__ u16 lB[128 * 32];

    const int t = threadIdx.x;
    const int lane = t & 63;
    const int wave = t >> 6;
    const int wr = wave >> 1, wc = wave & 1;     // 2x2 waves -> 64x64 each
    const int bm = blockIdx.y * 128, bn = blockIdx.x * 128;

    const int srow = t >> 2;
    const int scol = (t & 3) * 8;
    const size_t a0 = (size_t)(bm + srow) * K + scol;
    const size_t a1 = (size_t)(bm + 64 + srow) * K + scol;
    const size_t b0 = (size_t)(bn + srow) * K + scol;
    const size_t b1 = (size_t)(bn + 64 + srow) * K + scol;

    const int fr = lane & 15;
    const int fk = (lane >> 4) * 8;

    f32x4 acc[4][4];
    const f32x4 fzero = {0.f, 0.f, 0.f, 0.f};
#pragma unroll
    for (int i = 0; i < 4; ++i)
#pragma unroll
        for (int j = 0; j < 4; ++j) acc[i][j] = fzero;

    u16* ldsA = lA + wave * 512;
    u16* ldsB = lB + wave * 512;

    for (int k0 = 0; k0 < K; k0 += 32) {
        __builtin_amdgcn_global_load_lds(
            (const __attribute__((address_space(1))) void*)(A + a0 + k0),
            (__attribute__((address_space(3))) void*)(ldsA), 16, 0, 0);
        __builtin_amdgcn_global_load_lds(
            (const __attribute__((address_space(1))) void*)(A + a1 + k0),
            (__attribute__((address_space(3))) void*)(ldsA + 2048), 16, 0, 0);
        __builtin_amdgcn_global_load_lds(
            (const __attribute__((address_space(1))) void*)(Bm + b0 + k0),
            (__attribute__((address_space(3))) void*)(ldsB), 16, 0, 0);
        __builtin_amdgcn_global_load_lds(
            (const __attribute__((address_space(1))) void*)(Bm + b1 + k0),
            (__attribute__((address_space(3))) void*)(ldsB + 2048), 16, 0, 0);
        __syncthreads();

        bf16x8 af[4], bfv[4];
#pragma unroll
        for (int mi = 0; mi < 4; ++mi)
            af[mi] = *(const bf16x8*)&lA[(wr * 64 + mi * 16 + fr) * 32 + fk];
#pragma unroll
        for (int ni = 0; ni < 4; ++ni)
            bfv[ni] = *(const bf16x8*)&lB[(wc * 64 + ni * 16 + fr) * 32 + fk];
#pragma unroll
        for (int mi = 0; mi < 4; ++mi)
#pragma unroll
            for (int ni = 0; ni < 4; ++ni)
                acc[mi][ni] = __builtin_amdgcn_mfma_f32_16x16x32_bf16(
                    af[mi], bfv[ni], acc[mi][ni], 0, 0, 0);
        __syncthreads();
    }

    const int cr = (lane >> 4) * 4;
    const int cc = lane & 15;
#pragma unroll
    for (int mi = 0; mi < 4; ++mi) {
#pragma unroll
        for (int ni = 0; ni < 4; ++ni) {
            const int row = bm + wr * 64 + mi * 16 + cr;
            const int col = bn + wc * 64 + ni * 16 + cc;
            if constexpr (OUTMODE == 2) {
                // V^T layout (b,h,d,s): rows of C are s (4 consecutive), cols are h*128+d
                const int b = row >> 11, s0 = row & 2047;
                const int h = col >> 7, d = col & 127;
                u16x4 pk;
#pragma unroll
                for (int r = 0; r < 4; ++r) pk[r] = f2bf(acc[mi][ni][r]);
                *(u16x4*)((u16*)C + ((size_t)((b * 16 + h) * 128 + d)) * 2048 + s0) = pk;
            } else {
#pragma unroll
                for (int r = 0; r < 4; ++r) {
                    float val = acc[mi][ni][r];
                    size_t idx = (size_t)(row + r) * N + col;
                    if constexpr (OUTMODE == 0) ((u16*)C)[idx] = f2bf(val);
                    else                        ((float*)C)[idx] = val;
                }
            }
        }
    }
}

// ---------------------------------------------------------------- RoPE in place on (B*S, H*128) bf16
__global__ void k_rope(u16* __restrict__ x, int S, int n) {
    int i = blockIdx.x * blockDim.x + threadIdx.x;
    if (i >= n) return;
    const int j = i & 63;
    const int h = (i >> 6) & 15;
    const int row = i >> 10;
    const int s = row & (S - 1);
    const float L2B = 13.287712379549449f;
    float inv = exp2f(-(float)(2 * j) * (L2B / 128.f));
    float ang = (float)s * inv;
    float c, sn;
    sincosf(ang, &sn, &c);
    size_t base = (size_t)row * 2048 + h * 128 + j;
    float x1 = bf2f(x[base]);
    float x2 = bf2f(x[base + 64]);
    x[base]      = f2bf(x1 * c - x2 * sn);
    x[base + 64] = f2bf(x2 * c + x1 * sn);
}

// ---------------------------------------------------------------- MFMA flash attention (causal)
// 4 waves/block; wave owns 32 q-rows x 128 d. QB=128, KB=64.
// K LDS [64][128] bf16 + 16B-chunk XOR swizzle (chunk ^= kv&7)
// V LDS = V^T [128][64] bf16 + chunk swizzle (chunk ^= d&7); staged from global V^T (b,h,d,s)
// P per-wave LDS [32][72] u16 (stride 144B, 16B-aligned rows)
__global__ __launch_bounds__(256, 2) void k_flash_mfma(
    const u16* __restrict__ Q, const u16* __restrict__ K, const u16* __restrict__ VT,
    u16* __restrict__ O)
{
    constexpr int S = 2048, H = 16, HD = 2048;
    __shared__ __align__(16) u16 Kt[64 * 128];
    __shared__ __align__(16) u16 Vt[128 * 64];
    __shared__ __align__(16) u16 Pl[4][32 * 72];

    const int t = threadIdx.x;
    const int lane = t & 63;
    const int w = t >> 6;
    const int qt = blockIdx.x, h = blockIdx.y, b = blockIdx.z;
    const int q0 = qt * 128;
    const int wq0 = q0 + w * 32;

    const u16* qg = Q + ((size_t)b * S) * HD + h * 128;
    const u16* kg = K + ((size_t)b * S) * HD + h * 128;
    const u16* vg = VT + ((size_t)(b * H + h)) * 128 * S;

    const int r16 = lane & 15;
    const int g4 = lane >> 4;

    // Q fragments, pre-scaled by 1/sqrt(128)
    const float scale = 0.08838834764831845f;
    bf16x8 aQ[2][4];
#pragma unroll
    for (int qi = 0; qi < 2; ++qi) {
        const u16* qr = qg + (size_t)(wq0 + qi * 16 + r16) * HD;
#pragma unroll
        for (int dk = 0; dk < 4; ++dk) {
            u16x8 u = *(const u16x8*)(qr + dk * 32 + g4 * 8);
            u16x8 uu;
#pragma unroll
            for (int j = 0; j < 8; ++j) uu[j] = f2bf(bf2f(u[j]) * scale);
            aQ[qi][dk] = __builtin_bit_cast(bf16x8, uu);
        }
    }

    f32x4 oa[2][8];
    f32x4 mM[2], lL[2];
    const f32x4 fzero = {0.f, 0.f, 0.f, 0.f};
#pragma unroll
    for (int qi = 0; qi < 2; ++qi) {
        mM[qi] = f32x4{-1e30f, -1e30f, -1e30f, -1e30f};
        lL[qi] = fzero;
#pragma unroll
        for (int dj = 0; dj < 8; ++dj) oa[qi][dj] = fzero;
    }

    const int ntiles = (q0 + 128) / 64;
    for (int tix = 0; tix < ntiles; ++tix) {
        const int j0 = tix * 64;
        __syncthreads();   // prev tile's LDS reads done
        // ---- stage K tile (16 KB, 4 passes x 4 waves x 1 KB) — swizzled source, linear dest
#pragma unroll
        for (int p = 0; p < 4; ++p) {
            const int off = p * 4096 + w * 1024 + lane * 16;
            const int kv = off >> 8;
            const int c16 = (off >> 4) & 15;
            const u16* src = kg + (size_t)(j0 + kv) * HD + ((c16 ^ (kv & 7)) * 8);
            __builtin_amdgcn_global_load_lds(
                (const __attribute__((address_space(1))) void*)src,
                (__attribute__((address_space(3))) void*)((char*)Kt + p * 4096 + w * 1024), 16, 0, 0);
        }
        // ---- stage V^T tile (16 KB)
#pragma unroll
        for (int p = 0; p < 4; ++p) {
            const int off = p * 4096 + w * 1024 + lane * 16;
            const int d = off >> 7;
            const int c8 = (off >> 4) & 7;
            const u16* src = vg + (size_t)d * S + j0 + ((c8 ^ (d & 7)) * 8);
            __builtin_amdgcn_global_load_lds(
                (const __attribute__((address_space(1))) void*)src,
                (__attribute__((address_space(3))) void*)((char*)Vt + p * 4096 + w * 1024), 16, 0, 0);
        }
        __syncthreads();   // staging complete

        if (j0 > wq0 + 31) continue;   // fully-masked tile for this wave (barriers already passed)

        // ---- QK^T : S-tile 32q x 64kv
        f32x4 sc[2][4];
#pragma unroll
        for (int qi = 0; qi < 2; ++qi)
#pragma unroll
            for (int kf = 0; kf < 4; ++kf) sc[qi][kf] = fzero;

#pragma unroll
        for (int dk = 0; dk < 4; ++dk) {
            bf16x8 bK[4];
#pragma unroll
            for (int kf = 0; kf < 4; ++kf) {
                const int kv = kf * 16 + r16;
                const int c16 = g4 + dk * 4;
                bK[kf] = *(const bf16x8*)((const char*)Kt + kv * 256 + ((c16 ^ (kv & 7)) << 4));
            }
#pragma unroll
            for (int qi = 0; qi < 2; ++qi)
#pragma unroll
                for (int kf = 0; kf < 4; ++kf)
                    sc[qi][kf] = __builtin_amdgcn_mfma_f32_16x16x32_bf16(
                        aQ[qi][dk], bK[kf], sc[qi][kf], 0, 0, 0);
        }

        // ---- causal mask (C layout: row=(g4*4+r), col=r16)
        if (j0 + 63 > wq0) {
#pragma unroll
            for (int qi = 0; qi < 2; ++qi)
#pragma unroll
                for (int kf = 0; kf < 4; ++kf)
#pragma unroll
                    for (int r = 0; r < 4; ++r) {
                        const int row = wq0 + qi * 16 + g4 * 4 + r;
                        const int col = j0 + kf * 16 + r16;
                        if (col > row) sc[qi][kf][r] = -1e30f;
                    }
        }

        // ---- online softmax (per qi; rows live in 16-lane groups)
#pragma unroll
        for (int qi = 0; qi < 2; ++qi) {
            f32x4 rm = sc[qi][0];
#pragma unroll
            for (int kf = 1; kf < 4; ++kf)
#pragma unroll
                for (int r = 0; r < 4; ++r) rm[r] = fmaxf(rm[r], sc[qi][kf][r]);
#pragma unroll
            for (int r = 0; r < 4; ++r) {
                float v = rm[r];
                v = fmaxf(v, __shfl_xor(v, 1));
                v = fmaxf(v, __shfl_xor(v, 2));
                v = fmaxf(v, __shfl_xor(v, 4));
                v = fmaxf(v, __shfl_xor(v, 8));
                rm[r] = v;
            }
            f32x4 mn, al;
#pragma unroll
            for (int r = 0; r < 4; ++r) {
                mn[r] = fmaxf(mM[qi][r], rm[r]);
                al[r] = __expf(mM[qi][r] - mn[r]);
            }
            mM[qi] = mn;
            f32x4 rs = fzero;
#pragma unroll
            for (int kf = 0; kf < 4; ++kf)
#pragma unroll
                for (int r = 0; r < 4; ++r) {
                    float p = __expf(sc[qi][kf][r] - mn[r]);
                    sc[qi][kf][r] = p;
                    rs[r] += p;
                }
#pragma unroll
            for (int r = 0; r < 4; ++r) {
                float v = rs[r];
                v += __shfl_xor(v, 1);
                v += __shfl_xor(v, 2);
                v += __shfl_xor(v, 4);
                v += __shfl_xor(v, 8);
                rs[r] = v;
            }
#pragma unroll
            for (int r = 0; r < 4; ++r) lL[qi][r] = lL[qi][r] * al[r] + rs[r];
#pragma unroll
            for (int dj = 0; dj < 8; ++dj)
#pragma unroll
                for (int r = 0; r < 4; ++r) oa[qi][dj][r] *= al[r];
            // P -> per-wave LDS (bf16)
#pragma unroll
            for (int kf = 0; kf < 4; ++kf)
#pragma unroll
                for (int r = 0; r < 4; ++r)
                    Pl[w][(qi * 16 + g4 * 4 + r) * 72 + kf * 16 + r16] = f2bf(sc[qi][kf][r]);
        }

        // ---- PV : O += P @ V  (B-operand = V^T rows = d)
#pragma unroll
        for (int kvf = 0; kvf < 2; ++kvf) {
            bf16x8 pa[2];
#pragma unroll
            for (int qi = 0; qi < 2; ++qi)
                pa[qi] = *(const bf16x8*)&Pl[w][(qi * 16 + r16) * 72 + kvf * 32 + g4 * 8];
#pragma unroll
            for (int dj = 0; dj < 8; ++dj) {
                const int d = dj * 16 + r16;
                const int c8 = g4 + kvf * 4;
                bf16x8 bV = *(const bf16x8*)((const char*)Vt + d * 128 + ((c8 ^ (d & 7)) << 4));
#pragma unroll
                for (int qi = 0; qi < 2; ++qi)
                    oa[qi][dj] = __builtin_amdgcn_mfma_f32_16x16x32_bf16(
                        pa[qi], bV, oa[qi][dj], 0, 0, 0);
            }
        }
    }

    // ---- epilogue
#pragma unroll
    for (int qi = 0; qi < 2; ++qi) {
        f32x4 inv;
#pragma unroll
        for (int r = 0; r < 4; ++r) inv[r] = 1.f / lL[qi][r];
#pragma unroll
        for (int r = 0; r < 4; ++r) {
            u16* orow = O + (size_t)(b * S + wq0 + qi * 16 + g4 * 4 + r) * HD + h * 128;
#pragma unroll
            for (int dj = 0; dj < 8; ++dj)
                orow[dj * 16 + r16] = f2bf(oa[qi][dj][r] * inv[r]);
        }
    }
}

// ---------------------------------------------------------------- launch
extern "C" void kernel_launch(void* const* d_in, const int* in_sizes, int n_in,
                              void* d_out, int out_size, void* d_ws, size_t ws_size,
                              hipStream_t stream) {
    const float* hs = (const float*)d_in[0];
    const float* Wq = (const float*)d_in[1];
    const float* Wc = (const float*)d_in[2];
    const float* Wk = (const float*)d_in[3];
    const float* Wv = (const float*)d_in[4];
    const float* Wo = (const float*)d_in[5];

    const int B = 2, S = 2048, D = 2048, DL = 512, H = 16;
    const int M = B * S;   // 4096

    char* p = (char*)d_ws;
    u16* hs_bf = (u16*)p; p += (size_t)M * D * 2;
    u16* Wq_bf = (u16*)p; p += (size_t)D * D * 2;
    u16* Wc_bf = (u16*)p; p += (size_t)DL * D * 2;
    u16* Wk_bf = (u16*)p; p += (size_t)D * DL * 2;
    u16* Wv_bf = (u16*)p; p += (size_t)D * DL * 2;
    u16* Wo_bf = (u16*)p; p += (size_t)D * D * 2;
    u16* qb    = (u16*)p; p += (size_t)M * D * 2;
    u16* kb    = (u16*)p; p += (size_t)M * D * 2;
    u16* vbT   = (u16*)p; p += (size_t)M * D * 2;   // (B,H,128,S)
    u16* ckv   = (u16*)p; p += (size_t)M * DL * 2;
    u16* attn  = (u16*)p; p += (size_t)M * D * 2;

    auto conv = [&](const float* in, u16* out, size_t n) {
        int n4 = (int)(n / 4);
        int blocks = (n4 + 255) / 256;
        if (blocks > 4096) blocks = 4096;
        k_f32_to_bf16<<<blocks, 256, 0, stream>>>(in, out, n4);
    };
    conv(hs, hs_bf, (size_t)M * D);
    conv(Wq, Wq_bf, (size_t)D * D);
    conv(Wc, Wc_bf, (size_t)DL * D);
    conv(Wk, Wk_bf, (size_t)D * DL);
    conv(Wv, Wv_bf, (size_t)D * DL);
    conv(Wo, Wo_bf, (size_t)D * D);

    // q = hs @ Wq^T
    k_gemm_bt<0><<<dim3(D / 128, M / 128), 256, 0, stream>>>(hs_bf, Wq_bf, qb, M, D, D);
    // c_kv = hs @ Wc^T
    k_gemm_bt<0><<<dim3(DL / 128, M / 128), 256, 0, stream>>>(hs_bf, Wc_bf, ckv, M, DL, D);
    // k = c_kv @ Wk^T
    k_gemm_bt<0><<<dim3(D / 128, M / 128), 256, 0, stream>>>(ckv, Wk_bf, kb, M, D, DL);
    // v = c_kv @ Wv^T, written directly as V^T (b,h,d,s)
    k_gemm_bt<2><<<dim3(D / 128, M / 128), 256, 0, stream>>>(ckv, Wv_bf, vbT, M, D, DL);

    {
        int n = M * H * 64;
        int blocks = (n + 255) / 256;
        k_rope<<<blocks, 256, 0, stream>>>(qb, S, n);
        k_rope<<<blocks, 256, 0, stream>>>(kb, S, n);
    }

    k_flash_mfma<<<dim3(S / 128, H, B), 256, 0, stream>>>(qb, kb, vbT, attn);

    // out = attn @ Wo^T  (fp32 out)
    k_gemm_bt<1><<<dim3(D / 128, M / 128), 256, 0, stream>>>(attn, Wo_bf, (float*)d_out, M, D, D);
}